// Round 5
// baseline (150.310 us; speedup 1.0000x reference)
//
#include <hip/hip_runtime.h>

// B=4096, S=512, D=2, H=4. One 16-lane group per (batch, chunk) task:
// quad g = gate [i,u,f,o]; position p in quad holds j = (g odd ? 3-p : p)
// (reversal makes ROW_HALF_MIRROR pair same-j across g^1 in ONE DPP).
// Quad-cos: each lane computes all four z_j'/cos for its own gate from an
// in-register h-vector (h, h_{j^1}, h_{j^2}, h_{j^3} via XOR quad_perms),
// so no within-quad cumprod DPPs on the chain.
// Sequence chunking: chunk0 = steps [0,256) exact; chunk1 = 128-step warmup
// from zero state at t=128, stores [256,512). LSTM contraction (f<=0.731)
// makes the warmup residual ~2*L^128 << 0.02 threshold.

#define NS 512

static constexpr long SP_OFF  = 4194304;   // sampler_probs
static constexpr long EO_OFF  = 8388608;   // estimator_out
static constexpr long LO_OFF  = 10485760;  // lstm_out
static constexpr long FID_OFF = 18874368;  // fid_adj

template<int CTRL>
__device__ __forceinline__ float dppf(float v) {
    return __int_as_float(__builtin_amdgcn_mov_dpp(__float_as_int(v), CTRL, 0xF, 0xF, true));
}

// lanes in banks of BANK_MASK receive src permuted by CTRL; others keep old
template<int CTRL, int BANK_MASK>
__device__ __forceinline__ float dpp_merge(float old, float src) {
    return __int_as_float(__builtin_amdgcn_update_dpp(
        __float_as_int(old), __float_as_int(src), CTRL, 0xF, BANK_MASK, false));
}

// one LSTM step; X0,X1 inputs; K = substep (compile-time); HK = staging reg
#define STEP(X0, X1, K, HK)                                                        \
    {                                                                              \
        const float xzv0 = __builtin_fmaf(X1, wx1[0], __builtin_fmaf(X0, wx0[0], bthv[0])); \
        const float xzv1 = __builtin_fmaf(X1, wx1[1], __builtin_fmaf(X0, wx0[1], bthv[1])); \
        const float xzv2 = __builtin_fmaf(X1, wx1[2], __builtin_fmaf(X0, wx0[2], bthv[2])); \
        const float xzv3 = __builtin_fmaf(X1, wx1[3], __builtin_fmaf(X0, wx0[3], bthv[3])); \
        float z0 = __builtin_fmaf(h, whv[0][0], xzv0);                             \
        float z1 = __builtin_fmaf(h, whv[1][0], xzv1);                             \
        float z2 = __builtin_fmaf(h, whv[2][0], xzv2);                             \
        float z3 = __builtin_fmaf(h, whv[3][0], xzv3);                             \
        z0 = __builtin_fmaf(hx1, whv[0][1], z0);                                   \
        z1 = __builtin_fmaf(hx1, whv[1][1], z1);                                   \
        z2 = __builtin_fmaf(hx1, whv[2][1], z2);                                   \
        z3 = __builtin_fmaf(hx1, whv[3][1], z3);                                   \
        z0 = __builtin_fmaf(hx2, whv[0][2], z0);                                   \
        z1 = __builtin_fmaf(hx2, whv[1][2], z1);                                   \
        z2 = __builtin_fmaf(hx2, whv[2][2], z2);                                   \
        z3 = __builtin_fmaf(hx2, whv[3][2], z3);                                   \
        z0 = __builtin_fmaf(hx3, whv[0][3], z0);                                   \
        z1 = __builtin_fmaf(hx3, whv[1][3], z1);                                   \
        z2 = __builtin_fmaf(hx3, whv[2][3], z2);                                   \
        z3 = __builtin_fmaf(hx3, whv[3][3], z3);                                   \
        const float cc0 = __builtin_amdgcn_cosf(z0);                               \
        const float cc1 = __builtin_amdgcn_cosf(z1);                               \
        const float cc2 = __builtin_amdgcn_cosf(z2);                               \
        const float cc3 = __builtin_amdgcn_cosf(z3);                               \
        const float s0v = m0sel ? cc0 : 1.0f;                                      \
        const float s2v = m2sel ? cc2 : 1.0f;                                      \
        const float s3v = m3sel ? cc3 : 1.0f;                                      \
        const float m01 = s0v * cc1;   /* cc1 is in every output's factor set */   \
        const float m23 = s2v * s3v;                                               \
        const float y   = m01 * m23;                                               \
        const float y2  = y * y;                                                   \
        const float y4  = y2 * y2;                                                 \
        const float pa  = __builtin_fmaf(y2, B3, B1);                              \
        const float pb  = __builtin_fmaf(y2, B7, B5);                              \
        const float P   = __builtin_fmaf(y4, pb, pa);                              \
        const float act = __builtin_fmaf(y, P, sB);                                \
        const float hm  = dppf<0x141>(act);          /* act@(g^1), same j */       \
        const float pm  = act * hm;                  /* i*u on q0,q1 */            \
        const float iu  = dpp_merge<0x128, 0xC>(pm, pm);   /* q2,q3 <- ror8 */     \
        const float pf  = gb0 ? hm : act;            /* f on q2,q3 */              \
        const float po  = gb0 ? act : hm;            /* o on q2,q3 */              \
        const float fv  = dpp_merge<0x128, 0x3>(pf, pf);   /* q0,q1 <- ror8 */     \
        const float ov  = dpp_merge<0x128, 0x3>(po, po);                           \
        cst = __builtin_fmaf(fv, cst, iu);                                         \
        const float uq  = cst * cst;                                               \
        const float Nn  = __builtin_fmaf(uq, uq + 105.f, 945.f);                   \
        const float Dd  = __builtin_fmaf(uq, __builtin_fmaf(uq, 15.f, 420.f), 945.f); \
        const float oc  = ov * cst;                                                \
        const float Mv  = oc * Nn;                                                 \
        h = Mv * __builtin_amdgcn_rcpf(Dd);                                        \
        hx1 = dppf<0xB1>(h);   /* h_{j^1} (XOR perms commute with reversal) */     \
        hx2 = dppf<0x4E>(h);   /* h_{j^2} */                                       \
        hx3 = dppf<0x1B>(h);   /* h_{j^3} */                                       \
        HK = dpp_merge<0xE4, (1 << (K))>(HK, h);  /* quad K keeps its h */         \
    }

#define STEP4(FA, FB, HK)        \
    STEP(FA.x, FA.y, 0, HK)      \
    STEP(FA.z, FA.w, 1, HK)      \
    STEP(FB.x, FB.y, 2, HK)      \
    STEP(FB.z, FB.w, 3, HK)

#define PHASE16(P0,P1,P2,P3,P4,P5,P6,P7)  \
    STEP4(P0, P1, hk0)                    \
    STEP4(P2, P3, hk1)                    \
    STEP4(P4, P5, hk2)                    \
    STEP4(P6, P7, hk3)

#define LOAD8(P0,P1,P2,P3,P4,P5,P6,P7, IDX)                         \
    { const int _i4 = (IDX);                                        \
      P0 = xv[_i4+0]; P1 = xv[_i4+1]; P2 = xv[_i4+2];               \
      P3 = xv[_i4+3]; P4 = xv[_i4+4]; P5 = xv[_i4+5];               \
      P6 = xv[_i4+6]; P7 = xv[_i4+7]; }

#define STORE4()                                                    \
    spp[0] = hk0; spp[16] = hk1; spp[32] = hk2; spp[48] = hk3;      \
    spp += 64;

__global__ __launch_bounds__(64) void qlstm_kernel(
    const float* __restrict__ xin,
    const float* __restrict__ Wi, const float* __restrict__ bi,
    const float* __restrict__ Wu, const float* __restrict__ bu,
    const float* __restrict__ Wf, const float* __restrict__ bf,
    const float* __restrict__ Wo, const float* __restrict__ bo,
    const float* __restrict__ ti, const float* __restrict__ tu,
    const float* __restrict__ tf, const float* __restrict__ to_,
    float* __restrict__ out)
{
    const int tid = threadIdx.x;
    const int gl  = tid & 15;
    const int g   = gl >> 2;
    const int pq  = gl & 3;
    const int j   = (g & 1) ? (3 - pq) : pq;   // odd quads store j reversed
    const int chunk = blockIdx.x & 1;          // uniform per wave
    const int b   = (blockIdx.x >> 1) * 4 + (tid >> 4);

    // gate order on quads: [i, u, f, o]
    const float* Wt; const float* bt; const float* tht;
    if      (g == 0) { Wt = Wi; bt = bi; tht = ti;  }
    else if (g == 1) { Wt = Wu; bt = bu; tht = tu;  }
    else if (g == 2) { Wt = Wf; bt = bf; tht = tf;  }
    else             { Wt = Wo; bt = bo; tht = to_; }

    // per-lane weights for ALL four j' targets; WH column order matches the
    // in-register h-vector layout (h_{j^k} in slot k). Prescaled by 1/2pi.
    const float I2P = 0.15915494309189535f;
    float wx0[4], wx1[4], bthv[4], whv[4][4];
    #pragma unroll
    for (int jp = 0; jp < 4; ++jp) {
        wx0[jp]  = Wt[jp*6 + 0] * I2P;
        wx1[jp]  = Wt[jp*6 + 1] * I2P;
        bthv[jp] = (bt[jp] + tht[jp]) * I2P;
        #pragma unroll
        for (int k = 0; k < 4; ++k)
            whv[jp][k] = Wt[jp*6 + 2 + (j ^ k)] * I2P;
    }

    // factor-inclusion masks: out0=c1c2c3, out1=c0c1, out2=c0c1c2, out3=all
    const bool m0sel = (j >= 1);
    const bool m2sel = (j != 1);
    const bool m3sel = (j == 0) || (j == 3);
    const bool gb0   = (g & 1);

    // activation: sigma lanes: 0.5+0.5*T(q/2); u lane: T(q); ysc folded into
    // per-lane coefficients. T = odd deg-7 poly (err <3e-4 on [-1,1]).
    const bool isU = (g == 1);
    const float B1 = isU ? 1.0f        : 0.25f;
    const float B3 = isU ? -0.33333333f: -0.020833333f;
    const float B5 = isU ? 0.123842f   : 0.0019350f;
    const float B7 = isU ? -0.028914f  : -0.00011295f;
    const float sB = isU ? 0.0f        : 0.5f;

    const long n0 = (long)b * NS;
    float* spp = out + LO_OFF + 4*n0 + (chunk ? 1024 : 0) + g*4 + j;

    const float4* xv = (const float4*)(xin + (long)b * (NS * 2));
    int t4 = chunk ? 64 : 0;            // float4 index (= step/2): t=128 start
    const int nit   = chunk ? 12 : 8;   // 2 phases (32 steps) per iteration
    const int sfrom = chunk ? 4  : 0;   // first 8 phases of chunk1 = warmup

    float h = 0.f, hx1 = 0.f, hx2 = 0.f, hx3 = 0.f, cst = 0.f;
    float hk0 = 0.f, hk1 = 0.f, hk2 = 0.f, hk3 = 0.f;

    float4 a0,a1,a2,a3,a4,a5,a6,a7;
    float4 b0,b1,b2,b3,b4,b5,b6,b7;
    LOAD8(a0,a1,a2,a3,a4,a5,a6,a7, t4)

    #pragma unroll 1
    for (int it = 0; it < nit; ++it) {
        int i1 = t4 + 8;  if (i1 > 248) i1 = 248;   // clamped prefetch
        LOAD8(b0,b1,b2,b3,b4,b5,b6,b7, i1)
        PHASE16(a0,a1,a2,a3,a4,a5,a6,a7)
        if (it >= sfrom) { STORE4() }
        int i2 = t4 + 16; if (i2 > 248) i2 = 248;
        LOAD8(a0,a1,a2,a3,a4,a5,a6,a7, i2)
        PHASE16(b0,b1,b2,b3,b4,b5,b6,b7)
        if (it >= sfrom) { STORE4() }
        t4 += 16;
    }
}

// Elementwise pass over lstm_out: sampler logits/probs + estimator (+ fid).
// P0 = 1/2 + (cosTh*cos p0 - sinTh*sin p0*sin p1)/2 ; probs0 = sigmoid(2*P0-1)
__global__ __launch_bounds__(256) void epilogue_kernel(
    const float* __restrict__ sw, const float* __restrict__ ew,
    float* __restrict__ out)
{
    const long idx = (long)blockIdx.x * 256 + threadIdx.x;   // 0 .. B*S-1
    const float thsum = sw[0] + sw[1] + sw[2] + sw[3];
    const float K1 = __cosf(thsum), K2 = __sinf(thsum), Ke = __sinf(ew[0]);

    const float2 hp = *(const float2*)(out + LO_OFF + idx * 4); // h0, h1
    const float s0 = __sinf(hp.x), c0 = __cosf(hp.x), s1 = __sinf(hp.y);
    const float Dv = __builtin_fmaf(K1, c0, -(K2 * s0 * s1));   // 2*P0-1
    const float P0 = __builtin_fmaf(0.5f, Dv, 0.5f);
    const float sp0 = __builtin_amdgcn_rcpf(1.f + __expf(-Dv));

    float2 sl; sl.x = P0;  sl.y = 1.f - P0;
    float2 sp; sp.x = sp0; sp.y = 1.f - sp0;
    ((float2*)out)[idx] = sl;
    ((float2*)(out + SP_OFF))[idx] = sp;
    out[EO_OFF + idx] = Ke * s0;

    if (idx < 262144) {   // fid_adj: 512x512 complete graph minus diagonal
        const int r = (int)idx >> 9, c = (int)idx & 511;
        out[FID_OFF + idx] = (r == c) ? 0.f : 1.f;
    }
}

extern "C" void kernel_launch(void* const* d_in, const int* in_sizes, int n_in,
                              void* d_out, int out_size, void* d_ws, size_t ws_size,
                              hipStream_t stream) {
    (void)in_sizes; (void)n_in; (void)d_ws; (void)ws_size; (void)out_size;
    const float* xin = (const float*)d_in[0];
    const float* Wf  = (const float*)d_in[1];  const float* bf = (const float*)d_in[2];
    const float* Wi  = (const float*)d_in[3];  const float* bi = (const float*)d_in[4];
    const float* Wu  = (const float*)d_in[5];  const float* bu = (const float*)d_in[6];
    const float* Wo  = (const float*)d_in[7];  const float* bo = (const float*)d_in[8];
    const float* tf  = (const float*)d_in[9];  const float* ti = (const float*)d_in[10];
    const float* tu  = (const float*)d_in[11]; const float* to_ = (const float*)d_in[12];
    const float* sw  = (const float*)d_in[13]; const float* ew = (const float*)d_in[14];
    float* out = (float*)d_out;

    hipLaunchKernelGGL(qlstm_kernel, dim3(2048), dim3(64), 0, stream,
                       xin, Wi, bi, Wu, bu, Wf, bf, Wo, bo,
                       ti, tu, tf, to_, out);
    hipLaunchKernelGGL(epilogue_kernel, dim3(2097152/256), dim3(256), 0, stream, sw, ew, out);
}

// Round 6
// 90.245 us; speedup vs baseline: 1.6656x; 1.6656x over previous
//
#include <hip/hip_runtime.h>

// B=4096, S=512, D=2, H=4. One 16-lane group per (batch, chunk) task:
// lane = g*4 + j, quads g = gates in order [i, u, f, o], j = hidden index.
// R4-proven step (prescaled-weight v_cos, 2-level DPP cumprod w/ overlapped
// select, Estrin deg-7 activation, bank-masked update_dpp gather, R5 Pade
// cell tanh). NEW: 4-way sequence chunking -- chunk k covers steps
// [128k, 128k+128); k>0 warms up from zero state at t=128k-64 (contraction
// rho~0.8 => residual ~rho^64 << bf16 floor). 4096 waves = 4/SIMD.

#define NS 512

static constexpr long SP_OFF  = 4194304;   // sampler_probs
static constexpr long EO_OFF  = 8388608;   // estimator_out
static constexpr long LO_OFF  = 10485760;  // lstm_out
static constexpr long FID_OFF = 18874368;  // fid_adj

template<int CTRL>
__device__ __forceinline__ float dppf(float v) {
    return __int_as_float(__builtin_amdgcn_mov_dpp(__float_as_int(v), CTRL, 0xF, 0xF, true));
}

// merge: lanes in banks of BANK_MASK receive src permuted by CTRL; others keep old
template<int CTRL, int BANK_MASK>
__device__ __forceinline__ float dpp_merge(float old, float src) {
    return __int_as_float(__builtin_amdgcn_update_dpp(
        __float_as_int(old), __float_as_int(src), CTRL, 0xF, BANK_MASK, false));
}

// value from lane (quad^1, same j): half-mirror maps (q,j)->(q^1,3-j); quad_perm[3,2,1,0] fixes j
__device__ __forceinline__ float xor4f(float v) {
    float t = dppf<0x141>(v);   // ROW_HALF_MIRROR
    return dppf<0x1B>(t);       // quad_perm [3,2,1,0]
}

// one LSTM step; X0,X1 = inputs, K = step&3 (compile-time), HK = staging reg
#define STEP(X0, X1, K, HK)                                                      \
    {                                                                            \
        const float xz  = __builtin_fmaf(X1, w1, __builtin_fmaf(X0, w0, bth));   \
        const float f1  = __builtin_fmaf(h,  wh0, xz);                           \
        const float T01 = __builtin_fmaf(h1, wh1, f1);                           \
        const float T23 = __builtin_fmaf(h3, wh3, h2 * wh2);                     \
        const float z   = T01 + T23;            /* in revolutions */             \
        const float cc  = __builtin_amdgcn_cosf(z);                              \
        const float c1x = dppf<0xB1>(cc);       /* c_{j^1} */                    \
        const float pr  = cc * c1x;             /* pair product */               \
        const float pr2 = dppf<0x4E>(pr);       /* other pair's product */       \
        const float LHS = jb0 ? pr : (jb1 ? cc : c1x);  /* [c1x,pr,cc,pr] */     \
        const float LHSy = LHS * ysc;                                            \
        const float RHS = isj1 ? 1.0f : pr2;    /* [pr2,1,pr2,pr2] */            \
        const float y   = LHSy * RHS;                                            \
        const float y2  = y * y;                                                 \
        const float y4  = y2 * y2;                                               \
        const float pa  = __builtin_fmaf(y2, A3, A0);                            \
        const float pb  = __builtin_fmaf(y2, A7, A5);                            \
        const float P   = __builtin_fmaf(y4, pb, pa);                            \
        const float act = __builtin_fmaf(y, P, sB);                              \
        const float x1v = xor4f(act);           /* act@(g^1) */                  \
        const float pmA = act * x1v;            /* i*u on q0,1; f*o on q2,3 */   \
        const float W   = gb0 ? x1v : act;                                       \
        const float V   = gb0 ? act : x1v;                                       \
        const float iu  = dpp_merge<0x128, 0xC>(pmA, pmA); /* q2,3 <- ror8 */    \
        const float fv  = dpp_merge<0x128, 0x3>(W, W);     /* all = act@q2 */    \
        const float ov  = dpp_merge<0x128, 0x3>(V, V);     /* all = act@q3 */    \
        cst = __builtin_fmaf(fv, cst, iu);                                       \
        const float u   = cst * cst;                                             \
        const float oc  = ov * cst;                                              \
        const float Nn  = __builtin_fmaf(u, u + 105.f, 945.f);                   \
        const float Dd  = __builtin_fmaf(u, __builtin_fmaf(u, 15.f, 420.f), 945.f);\
        const float M   = oc * Nn;                                               \
        h = M * __builtin_amdgcn_rcpf(Dd);                                       \
        h1 = dppf<0x39>(h);                                                      \
        h2 = dppf<0x4E>(h);                                                      \
        h3 = dppf<0x93>(h);                                                      \
        HK = dpp_merge<0xE4, (1 << (K))>(HK, h);  /* bank K keeps its h */       \
    }

// 4 steps from two float4s (steps: FA.xy, FA.zw, FB.xy, FB.zw)
#define STEP4(FA, FB, HK)        \
    STEP(FA.x, FA.y, 0, HK)      \
    STEP(FA.z, FA.w, 1, HK)      \
    STEP(FB.x, FB.y, 2, HK)      \
    STEP(FB.z, FB.w, 3, HK)

#define PHASE16(P0,P1,P2,P3,P4,P5,P6,P7)  \
    STEP4(P0, P1, hk0)                    \
    STEP4(P2, P3, hk1)                    \
    STEP4(P4, P5, hk2)                    \
    STEP4(P6, P7, hk3)

#define LOAD8(P0,P1,P2,P3,P4,P5,P6,P7, IDX)                         \
    { const int _i4 = (IDX);                                        \
      P0 = xv[_i4+0]; P1 = xv[_i4+1]; P2 = xv[_i4+2];               \
      P3 = xv[_i4+3]; P4 = xv[_i4+4]; P5 = xv[_i4+5];               \
      P6 = xv[_i4+6]; P7 = xv[_i4+7]; }

#define STORE4()                                                    \
    spp[0] = hk0; spp[16] = hk1; spp[32] = hk2; spp[48] = hk3;      \
    spp += 64;

__global__ __launch_bounds__(64) void qlstm_kernel(
    const float* __restrict__ xin,
    const float* __restrict__ Wi, const float* __restrict__ bi,
    const float* __restrict__ Wu, const float* __restrict__ bu,
    const float* __restrict__ Wf, const float* __restrict__ bf,
    const float* __restrict__ Wo, const float* __restrict__ bo,
    const float* __restrict__ ti, const float* __restrict__ tu,
    const float* __restrict__ tf, const float* __restrict__ to_,
    float* __restrict__ out)
{
    const int tid   = threadIdx.x;
    const int gl    = tid & 15;
    const int g     = gl >> 2;
    const int j     = gl & 3;
    const int chunk = blockIdx.x & 3;               // uniform per block
    const int b     = (blockIdx.x >> 2) * 4 + (tid >> 4);

    // gate order on quads: [i, u, f, o]
    const float* Wt; const float* bt; const float* tht;
    if      (g == 0) { Wt = Wi; bt = bi; tht = ti;  }
    else if (g == 1) { Wt = Wu; bt = bu; tht = tu;  }
    else if (g == 2) { Wt = Wf; bt = bf; tht = tf;  }
    else             { Wt = Wo; bt = bo; tht = to_; }

    // weights prescaled by 1/(2*pi) so v_cos takes revolutions directly;
    // x-part, then h-part permuted to match rotation order h_{j+m}
    const float I2P = 0.15915494309189535f;
    const float w0  = Wt[j*6 + 0] * I2P, w1 = Wt[j*6 + 1] * I2P;
    const float wh0 = Wt[j*6 + 2 +  j]        * I2P;
    const float wh1 = Wt[j*6 + 2 + ((j+1)&3)] * I2P;
    const float wh2 = Wt[j*6 + 2 + ((j+2)&3)] * I2P;
    const float wh3 = Wt[j*6 + 2 + ((j+3)&3)] * I2P;
    const float bth = (bt[j] + tht[j]) * I2P;  // theta folded into bias (angles add)

    const bool isU = (g == 1);
    const bool jb0 = (j & 1), jb1 = (j & 2) != 0;
    const bool gb0 = (g & 1);
    const bool isj1 = (j == 1);

    // activation: sigma(q)=0.5+0.5*T(q/2); tanh(q)=T(q); T = odd deg-7 poly
    // per-lane folded coeffs: act = fma(y, A0+A3 y2+A5 y4+A7 y6, sB)
    const float ysc = isU ? 1.0f : 0.5f;
    const float sAv = isU ? 1.0f : 0.5f;
    const float sB  = isU ? 0.0f : 0.5f;
    const float A0 = sAv, A3 = sAv * -0.33333333f,
                A5 = sAv * 0.123842f, A7 = sAv * -0.028914f;

    const long n0 = (long)b * NS;
    // chunk k stores steps [128k, 128k+128): 512 floats per chunk
    float* spp = out + LO_OFF + 4*n0 + chunk*512 + gl;

    const float4* xv = (const float4*)(xin + (long)b * (NS * 2));
    // chunk0: start t=0, 8 phases, store all. chunk k>0: start t=128k-64,
    // 12 phases, first 4 phases (64 steps) are warmup (no store).
    int t4 = chunk ? (chunk*64 - 32) : 0;   // float4 index = step/2
    const int nit   = chunk ? 6 : 4;        // iterations of 2 phases each
    const int sfrom = chunk ? 2 : 0;        // store from this iteration on

    float h = 0.f, h1 = 0.f, h2 = 0.f, h3 = 0.f, cst = 0.f;
    float hk0 = 0.f, hk1 = 0.f, hk2 = 0.f, hk3 = 0.f;

    float4 a0,a1,a2,a3,a4,a5,a6,a7;
    float4 b0,b1,b2,b3,b4,b5,b6,b7;
    LOAD8(a0,a1,a2,a3,a4,a5,a6,a7, t4)

    #pragma unroll 1
    for (int it = 0; it < nit; ++it) {
        int i1 = t4 + 8;  if (i1 > 248) i1 = 248;   // clamped prefetch
        LOAD8(b0,b1,b2,b3,b4,b5,b6,b7, i1)
        PHASE16(a0,a1,a2,a3,a4,a5,a6,a7)
        if (it >= sfrom) { STORE4() }
        int i2 = t4 + 16; if (i2 > 248) i2 = 248;
        LOAD8(a0,a1,a2,a3,a4,a5,a6,a7, i2)
        PHASE16(b0,b1,b2,b3,b4,b5,b6,b7)
        if (it >= sfrom) { STORE4() }
        t4 += 16;
    }
}

// Elementwise pass over lstm_out: sampler logits/probs + estimator (+ fid).
// P0 = 1/2 + (cosTh*cos p0 - sinTh*sin p0*sin p1)/2 ; probs0 = sigmoid(2*P0-1)
__global__ __launch_bounds__(256) void epilogue_kernel(
    const float* __restrict__ sw, const float* __restrict__ ew,
    float* __restrict__ out)
{
    const long idx = (long)blockIdx.x * 256 + threadIdx.x;   // 0 .. B*S-1
    const float thsum = sw[0] + sw[1] + sw[2] + sw[3];
    const float K1 = __cosf(thsum), K2 = __sinf(thsum), Ke = __sinf(ew[0]);

    const float2 hp = *(const float2*)(out + LO_OFF + idx * 4); // h0, h1
    const float s0 = __sinf(hp.x), c0 = __cosf(hp.x), s1 = __sinf(hp.y);
    const float Dv = __builtin_fmaf(K1, c0, -(K2 * s0 * s1));   // 2*P0-1
    const float P0 = __builtin_fmaf(0.5f, Dv, 0.5f);
    const float sp0 = __builtin_amdgcn_rcpf(1.f + __expf(-Dv));

    float2 sl; sl.x = P0;  sl.y = 1.f - P0;
    float2 sp; sp.x = sp0; sp.y = 1.f - sp0;
    ((float2*)out)[idx] = sl;
    ((float2*)(out + SP_OFF))[idx] = sp;
    out[EO_OFF + idx] = Ke * s0;

    if (idx < 262144) {   // fid_adj: 512x512 complete graph minus diagonal
        const int r = (int)idx >> 9, c = (int)idx & 511;
        out[FID_OFF + idx] = (r == c) ? 0.f : 1.f;
    }
}

extern "C" void kernel_launch(void* const* d_in, const int* in_sizes, int n_in,
                              void* d_out, int out_size, void* d_ws, size_t ws_size,
                              hipStream_t stream) {
    (void)in_sizes; (void)n_in; (void)d_ws; (void)ws_size; (void)out_size;
    const float* xin = (const float*)d_in[0];
    const float* Wf  = (const float*)d_in[1];  const float* bf = (const float*)d_in[2];
    const float* Wi  = (const float*)d_in[3];  const float* bi = (const float*)d_in[4];
    const float* Wu  = (const float*)d_in[5];  const float* bu = (const float*)d_in[6];
    const float* Wo  = (const float*)d_in[7];  const float* bo = (const float*)d_in[8];
    const float* tf  = (const float*)d_in[9];  const float* ti = (const float*)d_in[10];
    const float* tu  = (const float*)d_in[11]; const float* to_ = (const float*)d_in[12];
    const float* sw  = (const float*)d_in[13]; const float* ew = (const float*)d_in[14];
    float* out = (float*)d_out;

    hipLaunchKernelGGL(qlstm_kernel, dim3(4096), dim3(64), 0, stream,
                       xin, Wi, bi, Wu, bu, Wf, bf, Wo, bo,
                       ti, tu, tf, to_, out);
    hipLaunchKernelGGL(epilogue_kernel, dim3(2097152/256), dim3(256), 0, stream, sw, ew, out);
}

// Round 7
// 72.730 us; speedup vs baseline: 2.0667x; 1.2408x over previous
//
#include <hip/hip_runtime.h>

// B=4096, S=512, D=2, H=4. One 16-lane group per (batch, chunk) task:
// lane = g*4 + j, quads g = gates in order [i, u, f, o], j = hidden index.
// R4-proven step (prescaled-weight v_cos, 2-level DPP cumprod w/ overlapped
// select, deg-7 odd-poly activation, bank-masked update_dpp gather, R5 Pade
// cell tanh). Balanced 4-way chunking: chunk0 stores [0,176) (no warmup);
// chunk k>0 warms up 64 steps from zero state at 112k and stores
// [176+(k-1)*112, ...+112). ALL waves run exactly 11 phases = 176 steps.
// 256-thread blocks co-locate the 4 chunks of 4 batches on one CU.

#define NS 512

static constexpr long SP_OFF  = 4194304;   // sampler_probs
static constexpr long EO_OFF  = 8388608;   // estimator_out
static constexpr long LO_OFF  = 10485760;  // lstm_out
static constexpr long FID_OFF = 18874368;  // fid_adj

template<int CTRL>
__device__ __forceinline__ float dppf(float v) {
    return __int_as_float(__builtin_amdgcn_mov_dpp(__float_as_int(v), CTRL, 0xF, 0xF, true));
}

// merge: lanes in banks of BANK_MASK receive src permuted by CTRL; others keep old
template<int CTRL, int BANK_MASK>
__device__ __forceinline__ float dpp_merge(float old, float src) {
    return __int_as_float(__builtin_amdgcn_update_dpp(
        __float_as_int(old), __float_as_int(src), CTRL, 0xF, BANK_MASK, false));
}

// value from lane (quad^1, same j): half-mirror maps (q,j)->(q^1,3-j); quad_perm[3,2,1,0] fixes j
__device__ __forceinline__ float xor4f(float v) {
    float t = dppf<0x141>(v);   // ROW_HALF_MIRROR
    return dppf<0x1B>(t);       // quad_perm [3,2,1,0]
}

// one LSTM step; X0,X1 = inputs, K = step&3 (compile-time), HK = staging reg
#define STEP(X0, X1, K, HK)                                                      \
    {                                                                            \
        const float xz  = __builtin_fmaf(X1, w1, __builtin_fmaf(X0, w0, bth));   \
        const float f1  = __builtin_fmaf(h,  wh0, xz);                           \
        const float T01 = __builtin_fmaf(h1, wh1, f1);                           \
        const float T23 = __builtin_fmaf(h3, wh3, h2 * wh2);                     \
        const float z   = T01 + T23;            /* in revolutions */             \
        const float cc  = __builtin_amdgcn_cosf(z);                              \
        const float c1x = dppf<0xB1>(cc);       /* c_{j^1} */                    \
        const float pr  = cc * c1x;             /* pair product */               \
        const float pr2 = dppf<0x4E>(pr);       /* other pair's product */       \
        const float LHS = jb0 ? pr : (jb1 ? cc : c1x);  /* [c1x,pr,cc,pr] */     \
        const float LHSy = LHS * ysc;                                            \
        const float RHS = isj1 ? 1.0f : pr2;    /* [pr2,1,pr2,pr2] */            \
        const float y   = LHSy * RHS;                                            \
        const float y2  = y * y;                                                 \
        float Pp = __builtin_fmaf(y2, A7, A5);                                   \
        Pp = __builtin_fmaf(y2, Pp, A3);                                         \
        Pp = __builtin_fmaf(y2, Pp, A0);                                         \
        const float act = __builtin_fmaf(y, Pp, sB);                             \
        const float x1v = xor4f(act);           /* act@(g^1) */                  \
        const float pmA = act * x1v;            /* i*u on q0,1; f*o on q2,3 */   \
        const float W   = gb0 ? x1v : act;                                       \
        const float V   = gb0 ? act : x1v;                                       \
        const float iu  = dpp_merge<0x128, 0xC>(pmA, pmA); /* q2,3 <- ror8 */    \
        const float fv  = dpp_merge<0x128, 0x3>(W, W);     /* all = act@q2 */    \
        const float ov  = dpp_merge<0x128, 0x3>(V, V);     /* all = act@q3 */    \
        cst = __builtin_fmaf(fv, cst, iu);                                       \
        const float u   = cst * cst;                                             \
        const float oc  = ov * cst;                                              \
        const float Nn  = __builtin_fmaf(u, u + 105.f, 945.f);                   \
        const float Dd  = __builtin_fmaf(u, __builtin_fmaf(u, 15.f, 420.f), 945.f);\
        const float M   = oc * Nn;                                               \
        h = M * __builtin_amdgcn_rcpf(Dd);                                       \
        h1 = dppf<0x39>(h);                                                      \
        h2 = dppf<0x4E>(h);                                                      \
        h3 = dppf<0x93>(h);                                                      \
        HK = dpp_merge<0xE4, (1 << (K))>(HK, h);  /* bank K keeps its h */       \
    }

// 4 steps from two float4s (steps: FA.xy, FA.zw, FB.xy, FB.zw)
#define STEP4(FA, FB, HK)        \
    STEP(FA.x, FA.y, 0, HK)      \
    STEP(FA.z, FA.w, 1, HK)      \
    STEP(FB.x, FB.y, 2, HK)      \
    STEP(FB.z, FB.w, 3, HK)

#define PHASE16(P0,P1,P2,P3,P4,P5,P6,P7)  \
    STEP4(P0, P1, hk0)                    \
    STEP4(P2, P3, hk1)                    \
    STEP4(P4, P5, hk2)                    \
    STEP4(P6, P7, hk3)

#define LOAD8(P0,P1,P2,P3,P4,P5,P6,P7, IDX)                         \
    { const int _i4 = (IDX);                                        \
      P0 = xv[_i4+0]; P1 = xv[_i4+1]; P2 = xv[_i4+2];               \
      P3 = xv[_i4+3]; P4 = xv[_i4+4]; P5 = xv[_i4+5];               \
      P6 = xv[_i4+6]; P7 = xv[_i4+7]; }

#define STORE4()                                                    \
    spp[0] = hk0; spp[16] = hk1; spp[32] = hk2; spp[48] = hk3;      \
    spp += 64;

__global__ __launch_bounds__(256) void qlstm_kernel(
    const float* __restrict__ xin,
    const float* __restrict__ Wi, const float* __restrict__ bi,
    const float* __restrict__ Wu, const float* __restrict__ bu,
    const float* __restrict__ Wf, const float* __restrict__ bf,
    const float* __restrict__ Wo, const float* __restrict__ bo,
    const float* __restrict__ ti, const float* __restrict__ tu,
    const float* __restrict__ tf, const float* __restrict__ to_,
    float* __restrict__ out)
{
    const int tid   = threadIdx.x;
    const int gl    = tid & 15;
    const int g     = gl >> 2;
    const int j     = gl & 3;
    const int wid   = blockIdx.x * 4 + (tid >> 6);   // global wave id
    const int chunk = wid & 3;                        // uniform per wave
    const int b     = (wid >> 2) * 4 + ((tid >> 4) & 3);

    // gate order on quads: [i, u, f, o]
    const float* Wt; const float* bt; const float* tht;
    if      (g == 0) { Wt = Wi; bt = bi; tht = ti;  }
    else if (g == 1) { Wt = Wu; bt = bu; tht = tu;  }
    else if (g == 2) { Wt = Wf; bt = bf; tht = tf;  }
    else             { Wt = Wo; bt = bo; tht = to_; }

    // weights prescaled by 1/(2*pi) so v_cos takes revolutions directly;
    // x-part, then h-part permuted to match rotation order h_{j+m}
    const float I2P = 0.15915494309189535f;
    const float w0  = Wt[j*6 + 0] * I2P, w1 = Wt[j*6 + 1] * I2P;
    const float wh0 = Wt[j*6 + 2 +  j]        * I2P;
    const float wh1 = Wt[j*6 + 2 + ((j+1)&3)] * I2P;
    const float wh2 = Wt[j*6 + 2 + ((j+2)&3)] * I2P;
    const float wh3 = Wt[j*6 + 2 + ((j+3)&3)] * I2P;
    const float bth = (bt[j] + tht[j]) * I2P;  // theta folded into bias (angles add)

    const bool isU = (g == 1);
    const bool jb0 = (j & 1), jb1 = (j & 2) != 0;
    const bool gb0 = (g & 1);
    const bool isj1 = (j == 1);

    // activation: sigma(q)=0.5+0.5*T(q/2); tanh(q)=T(q); T = odd deg-7 poly
    // per-lane folded coeffs: act = fma(y, A0+A3 y2+A5 y4+A7 y6, sB)
    const float ysc = isU ? 1.0f : 0.5f;
    const float sAv = isU ? 1.0f : 0.5f;
    const float sB  = isU ? 0.0f : 0.5f;
    const float A0 = sAv, A3 = sAv * -0.33333333f,
                A5 = sAv * 0.123842f, A7 = sAv * -0.028914f;

    // balanced chunks: stores cover [0,176) | [176,288) | [288,400) | [400,512)
    // chunk k>0 starts at step 112k with a 64-step warmup; all waves: 11 phases.
    const long n0 = (long)b * NS;
    const int store_start = chunk * 112 + (chunk ? 64 : 0);
    float* spp = out + LO_OFF + 4*n0 + 4*store_start + gl;

    const float4* xv = (const float4*)(xin + (long)b * (NS * 2));
    int t4 = chunk * 56;                   // float4 index = start_step/2
    const bool stAll = (chunk == 0);       // chunk0 stores every phase

    float h = 0.f, h1 = 0.f, h2 = 0.f, h3 = 0.f, cst = 0.f;
    float hk0 = 0.f, hk1 = 0.f, hk2 = 0.f, hk3 = 0.f;

    float4 a0,a1,a2,a3,a4,a5,a6,a7;
    float4 b0,b1,b2,b3,b4,b5,b6,b7;
    LOAD8(a0,a1,a2,a3,a4,a5,a6,a7, t4)     // phase 0

    // 11 phases: 5 double-phases + 1 tail. Max load index = 168+80+7 = 255.
    #pragma unroll 1
    for (int m = 0; m < 5; ++m) {
        LOAD8(b0,b1,b2,b3,b4,b5,b6,b7, t4 + 8)     // phase 2m+1
        PHASE16(a0,a1,a2,a3,a4,a5,a6,a7)           // phase 2m
        if (stAll || m >= 2) { STORE4() }
        LOAD8(a0,a1,a2,a3,a4,a5,a6,a7, t4 + 16)    // phase 2m+2
        PHASE16(b0,b1,b2,b3,b4,b5,b6,b7)           // phase 2m+1
        if (stAll || m >= 2) { STORE4() }
        t4 += 16;
    }
    PHASE16(a0,a1,a2,a3,a4,a5,a6,a7)               // phase 10
    STORE4()
}

// Elementwise pass over lstm_out: sampler logits/probs + estimator (+ fid).
// P0 = 1/2 + (cosTh*cos p0 - sinTh*sin p0*sin p1)/2 ; probs0 = sigmoid(2*P0-1)
__global__ __launch_bounds__(256) void epilogue_kernel(
    const float* __restrict__ sw, const float* __restrict__ ew,
    float* __restrict__ out)
{
    const long idx = (long)blockIdx.x * 256 + threadIdx.x;   // 0 .. B*S-1
    const float thsum = sw[0] + sw[1] + sw[2] + sw[3];
    const float K1 = __cosf(thsum), K2 = __sinf(thsum), Ke = __sinf(ew[0]);

    const float2 hp = *(const float2*)(out + LO_OFF + idx * 4); // h0, h1
    const float s0 = __sinf(hp.x), c0 = __cosf(hp.x), s1 = __sinf(hp.y);
    const float Dv = __builtin_fmaf(K1, c0, -(K2 * s0 * s1));   // 2*P0-1
    const float P0 = __builtin_fmaf(0.5f, Dv, 0.5f);
    const float sp0 = __builtin_amdgcn_rcpf(1.f + __expf(-Dv));

    float2 sl; sl.x = P0;  sl.y = 1.f - P0;
    float2 sp; sp.x = sp0; sp.y = 1.f - sp0;
    ((float2*)out)[idx] = sl;
    ((float2*)(out + SP_OFF))[idx] = sp;
    out[EO_OFF + idx] = Ke * s0;

    if (idx < 262144) {   // fid_adj: 512x512 complete graph minus diagonal
        const int r = (int)idx >> 9, c = (int)idx & 511;
        out[FID_OFF + idx] = (r == c) ? 0.f : 1.f;
    }
}

extern "C" void kernel_launch(void* const* d_in, const int* in_sizes, int n_in,
                              void* d_out, int out_size, void* d_ws, size_t ws_size,
                              hipStream_t stream) {
    (void)in_sizes; (void)n_in; (void)d_ws; (void)ws_size; (void)out_size;
    const float* xin = (const float*)d_in[0];
    const float* Wf  = (const float*)d_in[1];  const float* bf = (const float*)d_in[2];
    const float* Wi  = (const float*)d_in[3];  const float* bi = (const float*)d_in[4];
    const float* Wu  = (const float*)d_in[5];  const float* bu = (const float*)d_in[6];
    const float* Wo  = (const float*)d_in[7];  const float* bo = (const float*)d_in[8];
    const float* tf  = (const float*)d_in[9];  const float* ti = (const float*)d_in[10];
    const float* tu  = (const float*)d_in[11]; const float* to_ = (const float*)d_in[12];
    const float* sw  = (const float*)d_in[13]; const float* ew = (const float*)d_in[14];
    float* out = (float*)d_out;

    hipLaunchKernelGGL(qlstm_kernel, dim3(1024), dim3(256), 0, stream,
                       xin, Wi, bi, Wu, bu, Wf, bf, Wo, bo,
                       ti, tu, tf, to_, out);
    hipLaunchKernelGGL(epilogue_kernel, dim3(2097152/256), dim3(256), 0, stream, sw, ew, out);
}